// Round 15
// baseline (100.525 us; speedup 1.0000x reference)
//
#include <hip/hip_runtime.h>
#include <math.h>

// Problem constants (match reference setup_inputs)
#define TT 4096
#define DD 512
#define EE 64
#define HH 4
#define G1 256      // D/2
#define TP 16       // positions per block
#define NWAVE 4

typedef short  s16x8 __attribute__((ext_vector_type(8)));
typedef short  s16x4 __attribute__((ext_vector_type(4)));
typedef float  f32x4 __attribute__((ext_vector_type(4)));
typedef float  f32x2 __attribute__((ext_vector_type(2)));

__device__ __forceinline__ unsigned short f2bf(float f) {
    union { float f; unsigned u; } v; v.f = f;
    unsigned r = v.u + 0x7FFFu + ((v.u >> 16) & 1u);   // RNE
    return (unsigned short)(r >> 16);
}
__device__ __forceinline__ float bf2f(unsigned short b) {
    union { unsigned u; float f; } v; v.u = ((unsigned)b) << 16;
    return v.f;
}

#define WS_WHID 0
#define WS_WG1  (DD * EE)

// ---- pre-pass: convert weights to bf16 in FRAGMENT-MAJOR order (round-14 win:
//      one contiguous 1KB load per wave A-fragment instead of 16 cache lines).
__global__ __launch_bounds__(256) void convert_weights(
    const float* __restrict__ W_hid, const float* __restrict__ W_g1,
    unsigned short* __restrict__ ws) {
    int i = blockIdx.x * 256 + threadIdx.x;
    if (i < DD * EE) {          // W_hid: Mt 0..31, ks 0..1
        const int j    = i & 7;
        const int lane = (i >> 3) & 63;
        const int ks   = (i >> 9) & 1;
        const int Mt   = i >> 10;
        const int row  = Mt * 16 + (lane & 15);
        const int col  = ks * 32 + (lane >> 4) * 8 + j;
        ws[WS_WHID + i] = f2bf(W_hid[row * EE + col]);
    }
    if (i < G1 * DD) {          // W_g1: Mt 0..15, ks 0..15
        const int j    = i & 7;
        const int lane = (i >> 3) & 63;
        const int ks   = (i >> 9) & 15;
        const int Mt   = i >> 13;
        const int row  = Mt * 16 + (lane & 15);
        const int col  = ks * 32 + (lane >> 4) * 8 + j;
        ws[WS_WG1 + i] = f2bf(W_g1[row * DD + col]);
    }
}

// LDS: sGb 16K + sPf 8K + sU 2K = 26.6 KB -> 6 blocks/CU (was 35 KB -> 4).
// VGPR already 64 -> (256,6) costs nothing in regalloc.
__global__ __launch_bounds__(256, 6) void engram_mfma(
    const int*   __restrict__ tok,     // [B,T]
    const float* __restrict__ hidden,  // [B,T,D]
    const float* __restrict__ emb,     // [H,HR,E]
    const float* __restrict__ b_hid,   // [D]
    const float* __restrict__ b_g1,    // [G1]
    const float* __restrict__ W_g2,    // [1,G1]
    const float* __restrict__ b_g2,    // [1]
    const int*   __restrict__ seeds,   // [H]
    const int*   __restrict__ p_hr,
    const int*   __restrict__ p_mn,
    const unsigned short* __restrict__ ws_bf,  // fragment-major W_hid | W_g1
    float*       __restrict__ out)     // [B,T,D]
{
    __shared__ __align__(16) unsigned char sGb[TP * 1024];  // g bf16 [16][512], swizzled
    __shared__ __align__(16) unsigned char sPf[TP * 512];   // proj fp8 [16][512], swizzled
    __shared__ __align__(16) unsigned char sU[2048];        // union: sMemb | {sGpart,sGate}

    unsigned char* sMemb = sU;                 // seq_mem bf16 [16][64], swizzled (P1-P3)
    float* sGpart = (float*)sU;                // [NWAVE][TP]           (P4+)
    float* sGate  = (float*)(sU + 512);        // [TP]                  (P5+)

    const int tid  = threadIdx.x;
    const int lane = tid & 63;
    const int wave = tid >> 6;
    const int lr   = lane & 15;   // operand row / C col (position)
    const int lg   = lane >> 4;   // k-group / C row-quad
    const int pg0  = blockIdx.x * TP;
    const int b    = pg0 / TT;
    const int t0   = pg0 % TT;
    const int HR   = *p_hr;
    int NN = *p_mn - 1;
    if (NN > 3) NN = 3;
    if (NN < 0) NN = 0;

    const unsigned short* ws_whid = ws_bf + WS_WHID;   // frag-major [32][2][64][8]
    const unsigned short* ws_wg1  = ws_bf + WS_WG1;    // frag-major [16][16][64][8]

    // ---- P1+P2 fused: per-thread hash (bit-exact fp32 replication) + gather
    {
        const int p = tid >> 4, q = tid & 15;   // q covers e = q*4 .. q*4+3
        const int t = t0 + p;
        const int* trow = tok + b * TT;
        const float tf0 = (float)trow[t];
        float acc[4] = {0.f, 0.f, 0.f, 0.f};
        #pragma unroll
        for (int h = 0; h < HH; ++h) {
            const float sd = (float)(seeds[h] + 1);
            float w = tf0 * sd;
            for (int j = 0; j < NN; ++j) {
                const int n = j + 2;
                if (t <= TT - n) {
                    w = w + (float)trow[t + n - 1] * sd;   // ((s0+s1)+s2) ordering
                    const int idx = ((int)w) % HR;
                    const float4 f = *(const float4*)(emb + ((size_t)h * 262144u + (size_t)idx) * EE + q * 4);
                    acc[0] += f.x; acc[1] += f.y; acc[2] += f.z; acc[3] += f.w;
                }
            }
        }
        s16x4 pk;
        #pragma unroll
        for (int k = 0; k < 4; ++k) pk[k] = (short)f2bf(acc[k] * 0.25f);
        const int c = q * 8;   // byte col
        *(s16x4*)(sMemb + p * 128 + (c ^ ((p & 7) << 4))) = pk;
    }
    __syncthreads();

    // ---- P3: projT[d][p] via MFMA (frag-major A); write proj+b as fp8 e4m3.
    {
        s16x8 bfrag[2];
        #pragma unroll
        for (int ks = 0; ks < 2; ++ks) {
            const int c = ks * 64 + lg * 16;
            bfrag[ks] = *(const s16x8*)(sMemb + lr * 128 + (c ^ ((lr & 7) << 4)));
        }
        #pragma unroll 2
        for (int m = 0; m < 8; ++m) {
            const int Mt = wave * 8 + m;
            s16x8 afrag[2];
            #pragma unroll
            for (int ks = 0; ks < 2; ++ks)
                afrag[ks] = *(const s16x8*)(ws_whid + (((Mt * 2) + ks) * 64 + lane) * 8);
            f32x4 c = {0.f, 0.f, 0.f, 0.f};
            c = __builtin_amdgcn_mfma_f32_16x16x32_bf16(afrag[0], bfrag[0], c, 0, 0, 0);
            c = __builtin_amdgcn_mfma_f32_16x16x32_bf16(afrag[1], bfrag[1], c, 0, 0, 0);
            // lane holds C[d = Mt*16+lg*4+r][p = lr]
            const int d0 = Mt * 16 + lg * 4;
            const float4 bh = *(const float4*)&b_hid[d0];
            const float pr0 = c[0] + bh.x, pr1 = c[1] + bh.y;
            const float pr2 = c[2] + bh.z, pr3 = c[3] + bh.w;
            int pk8 = __builtin_amdgcn_cvt_pk_fp8_f32(pr0, pr1, 0, false);
            pk8 = __builtin_amdgcn_cvt_pk_fp8_f32(pr2, pr3, pk8, true);
            *(int*)(sPf + lr * 512 + (d0 ^ ((lr & 7) << 2))) = pk8;
        }
    }
    __syncthreads();

    // ---- P3.5: lane-contiguous hidden pass: g = h + fp8(proj) -> sGb (bf16).
    //      Same fp8 value is reused in P6, so out = h + gate*p exactly.
    {
        f32x4 hreg[8];
        #pragma unroll
        for (int c4 = 0; c4 < 8; ++c4) {
            const int fidx = c4 * 256 + tid;          // float4 index in [0, 2048)
            hreg[c4] = *(const f32x4*)&hidden[(size_t)(pg0 + (fidx >> 7)) * DD + (fidx & 127) * 4];
        }
        #pragma unroll
        for (int c4 = 0; c4 < 8; ++c4) {
            const int fidx = c4 * 256 + tid;
            const int p    = fidx >> 7;
            const int d    = (fidx & 127) * 4;
            const int pk8  = *(const int*)(sPf + p * 512 + (d ^ ((p & 7) << 2)));
            const f32x2 plo = __builtin_amdgcn_cvt_pk_f32_fp8(pk8, false);
            const f32x2 phi = __builtin_amdgcn_cvt_pk_f32_fp8(pk8, true);
            s16x4 gp;
            gp[0] = (short)f2bf(hreg[c4][0] + plo[0]);
            gp[1] = (short)f2bf(hreg[c4][1] + plo[1]);
            gp[2] = (short)f2bf(hreg[c4][2] + phi[0]);
            gp[3] = (short)f2bf(hreg[c4][3] + phi[1]);
            *(s16x4*)(sGb + p * 1024 + ((d * 2) ^ ((p & 7) << 4))) = gp;
        }
    }
    __syncthreads();

    // ---- P4: g1T[h][p] GEMM over K=512; A-fragments coalesced (fragment-major)
    {
        float pgate = 0.f;
        f32x4 c[4];
        #pragma unroll
        for (int m = 0; m < 4; ++m) c[m] = (f32x4){0.f, 0.f, 0.f, 0.f};
        #pragma unroll 4
        for (int ks = 0; ks < 16; ++ks) {
            const int ccol = ks * 64 + lg * 16;
            const s16x8 gb = *(const s16x8*)(sGb + lr * 1024 + (ccol ^ ((lr & 7) << 4)));
            #pragma unroll
            for (int m = 0; m < 4; ++m) {
                const int Mt = wave * 4 + m;
                const s16x8 a = *(const s16x8*)(ws_wg1 + ((Mt * 16 + ks) * 64 + lane) * 8);
                c[m] = __builtin_amdgcn_mfma_f32_16x16x32_bf16(a, gb, c[m], 0, 0, 0);
            }
        }
        #pragma unroll
        for (int m = 0; m < 4; ++m) {
            // lane holds C[h = (wave*4+m)*16+lg*4+r][p = lr]
            const int h0 = (wave * 4 + m) * 16 + lg * 4;
            const float4 bg = *(const float4*)&b_g1[h0];
            const float4 w2 = *(const float4*)&W_g2[h0];
            #pragma unroll
            for (int r = 0; r < 4; ++r) {
                const float x = c[m][r] + ((const float*)&bg)[r];
                const float gl = 0.5f * x * (1.0f + erff(x * 0.70710678118654752f));
                pgate += gl * ((const float*)&w2)[r];
            }
        }
        pgate += __shfl_xor(pgate, 16);
        pgate += __shfl_xor(pgate, 32);
        if (lane < 16) sGpart[wave * TP + lane] = pgate;
    }
    __syncthreads();
    if (tid < TP) {
        const float s = sGpart[0 * TP + tid] + sGpart[1 * TP + tid]
                      + sGpart[2 * TP + tid] + sGpart[3 * TP + tid] + b_g2[0];
        sGate[tid] = 1.0f / (1.0f + expf(-s));
    }
    __syncthreads();

    // ---- P6: out = g - (1-gate)*fp8(proj), plain cached float4 stores
    {
        #pragma unroll
        for (int c4 = 0; c4 < 8; ++c4) {
            const int fidx = c4 * 256 + tid;          // float4 index in [0, 2048)
            const int p    = fidx >> 7;               // 128 float4 per position
            const int d    = (fidx & 127) * 4;
            const float cg = 1.0f - sGate[p];
            const size_t row = (size_t)(pg0 + p) * DD;
            const s16x4 gv = *(const s16x4*)(sGb + p * 1024 + ((d * 2) ^ ((p & 7) << 4)));
            const int  pk8 = *(const int*)(sPf + p * 512 + (d ^ ((p & 7) << 2)));
            const f32x2 plo = __builtin_amdgcn_cvt_pk_f32_fp8(pk8, false);
            const f32x2 phi = __builtin_amdgcn_cvt_pk_f32_fp8(pk8, true);
            f32x4 o;
            o[0] = bf2f((unsigned short)gv[0]) - cg * plo[0];
            o[1] = bf2f((unsigned short)gv[1]) - cg * plo[1];
            o[2] = bf2f((unsigned short)gv[2]) - cg * phi[0];
            o[3] = bf2f((unsigned short)gv[3]) - cg * phi[1];
            *(f32x4*)&out[row + d] = o;
        }
    }
}

extern "C" void kernel_launch(void* const* d_in, const int* in_sizes, int n_in,
                              void* d_out, int out_size, void* d_ws, size_t ws_size,
                              hipStream_t stream) {
    const int*   tok    = (const int*)  d_in[0];
    const float* hidden = (const float*)d_in[1];
    const float* emb    = (const float*)d_in[2];
    const float* W_hid  = (const float*)d_in[3];
    const float* b_hid  = (const float*)d_in[4];
    const float* W_g1   = (const float*)d_in[5];
    const float* b_g1   = (const float*)d_in[6];
    const float* W_g2   = (const float*)d_in[7];
    const float* b_g2   = (const float*)d_in[8];
    const int*   seeds  = (const int*)  d_in[9];
    const int*   p_hr   = (const int*)  d_in[10];
    const int*   p_mn   = (const int*)  d_in[11];
    float* out = (float*)d_out;
    unsigned short* ws_bf = (unsigned short*)d_ws;

    convert_weights<<<dim3((G1 * DD + 255) / 256), dim3(256), 0, stream>>>(W_hid, W_g1, ws_bf);

    const int npos = in_sizes[1] / DD;   // B*T
    engram_mfma<<<dim3(npos / TP), dim3(256), 0, stream>>>(
        tok, hidden, emb, b_hid, b_g1, W_g2, b_g2, seeds, p_hr, p_mn, ws_bf, out);
}

// Round 16
// 73.200 us; speedup vs baseline: 1.3733x; 1.3733x over previous
//
#include <hip/hip_runtime.h>
#include <math.h>

// Problem constants (match reference setup_inputs)
#define TT 4096
#define DD 512
#define EE 64
#define HH 4
#define G1 256      // D/2
#define TP 16       // positions per block
#define NWAVE 4

typedef short  s16x8 __attribute__((ext_vector_type(8)));
typedef short  s16x4 __attribute__((ext_vector_type(4)));
typedef float  f32x4 __attribute__((ext_vector_type(4)));

__device__ __forceinline__ unsigned short f2bf(float f) {
    union { float f; unsigned u; } v; v.f = f;
    unsigned r = v.u + 0x7FFFu + ((v.u >> 16) & 1u);   // RNE
    return (unsigned short)(r >> 16);
}
__device__ __forceinline__ float bf2f(unsigned short b) {
    union { unsigned u; float f; } v; v.u = ((unsigned)b) << 16;
    return v.f;
}

#define WS_WHID 0
#define WS_WG1  (DD * EE)

// ---- pre-pass: convert weights to bf16 in FRAGMENT-MAJOR order (round-14 win:
//      one contiguous 1KB load per wave A-fragment instead of 16 cache lines).
__global__ __launch_bounds__(256) void convert_weights(
    const float* __restrict__ W_hid, const float* __restrict__ W_g1,
    unsigned short* __restrict__ ws) {
    int i = blockIdx.x * 256 + threadIdx.x;
    if (i < DD * EE) {          // W_hid: Mt 0..31, ks 0..1
        const int j    = i & 7;
        const int lane = (i >> 3) & 63;
        const int ks   = (i >> 9) & 1;
        const int Mt   = i >> 10;
        const int row  = Mt * 16 + (lane & 15);
        const int col  = ks * 32 + (lane >> 4) * 8 + j;
        ws[WS_WHID + i] = f2bf(W_hid[row * EE + col]);
    }
    if (i < G1 * DD) {          // W_g1: Mt 0..15, ks 0..15
        const int j    = i & 7;
        const int lane = (i >> 3) & 63;
        const int ks   = (i >> 9) & 15;
        const int Mt   = i >> 13;
        const int row  = Mt * 16 + (lane & 15);
        const int col  = ks * 32 + (lane >> 4) * 8 + j;
        ws[WS_WG1 + i] = f2bf(W_g1[row * DD + col]);
    }
}

__global__ __launch_bounds__(256, 4) void engram_mfma(
    const int*   __restrict__ tok,     // [B,T]
    const float* __restrict__ hidden,  // [B,T,D]
    const float* __restrict__ emb,     // [H,HR,E]
    const float* __restrict__ b_hid,   // [D]
    const float* __restrict__ b_g1,    // [G1]
    const float* __restrict__ W_g2,    // [1,G1]
    const float* __restrict__ b_g2,    // [1]
    const int*   __restrict__ seeds,   // [H]
    const int*   __restrict__ p_hr,
    const int*   __restrict__ p_mn,
    const unsigned short* __restrict__ ws_bf,  // fragment-major W_hid | W_g1
    float*       __restrict__ out)     // [B,T,D]
{
    __shared__ __align__(16) unsigned char sMemb[TP * 128];   // seq_mem bf16 [16][64], swizzled
    __shared__ __align__(16) unsigned char sGb[TP * 1024];    // g    bf16 [16][512], swizzled
    __shared__ __align__(16) unsigned char sPb[TP * 1024];    // proj bf16 [16][512], swizzled
    __shared__ float sGpart[NWAVE][TP];
    __shared__ float sGate[TP];

    const int tid  = threadIdx.x;
    const int lane = tid & 63;
    const int wave = tid >> 6;
    const int lr   = lane & 15;   // operand row / C col (position)
    const int lg   = lane >> 4;   // k-group / C row-quad
    const int pg0  = blockIdx.x * TP;
    const int b    = pg0 / TT;
    const int t0   = pg0 % TT;
    const int HR   = *p_hr;
    int NN = *p_mn - 1;
    if (NN > 3) NN = 3;
    if (NN < 0) NN = 0;

    const unsigned short* ws_whid = ws_bf + WS_WHID;   // frag-major [32][2][64][8]
    const unsigned short* ws_wg1  = ws_bf + WS_WG1;    // frag-major [16][16][64][8]

    // ---- P1+P2 fused: per-thread hash (bit-exact fp32 replication) + gather
    {
        const int p = tid >> 4, q = tid & 15;   // q covers e = q*4 .. q*4+3
        const int t = t0 + p;
        const int* trow = tok + b * TT;
        const float tf0 = (float)trow[t];
        float acc[4] = {0.f, 0.f, 0.f, 0.f};
        #pragma unroll
        for (int h = 0; h < HH; ++h) {
            const float sd = (float)(seeds[h] + 1);
            float w = tf0 * sd;
            for (int j = 0; j < NN; ++j) {
                const int n = j + 2;
                if (t <= TT - n) {
                    w = w + (float)trow[t + n - 1] * sd;   // ((s0+s1)+s2) ordering
                    const int idx = ((int)w) % HR;
                    const float4 f = *(const float4*)(emb + ((size_t)h * 262144u + (size_t)idx) * EE + q * 4);
                    acc[0] += f.x; acc[1] += f.y; acc[2] += f.z; acc[3] += f.w;
                }
            }
        }
        s16x4 pk;
        #pragma unroll
        for (int k = 0; k < 4; ++k) pk[k] = (short)f2bf(acc[k] * 0.25f);
        const int c = q * 8;   // byte col
        *(s16x4*)(sMemb + p * 128 + (c ^ ((p & 7) << 4))) = pk;
    }
    __syncthreads();

    // ---- P3: projT[d][p] via MFMA; write proj+b (bf16, swizzled) ONLY.
    //      A-fragments ONE coalesced 1KB load per wave (fragment-major).
    {
        s16x8 bfrag[2];
        #pragma unroll
        for (int ks = 0; ks < 2; ++ks) {
            const int c = ks * 64 + lg * 16;
            bfrag[ks] = *(const s16x8*)(sMemb + lr * 128 + (c ^ ((lr & 7) << 4)));
        }
        #pragma unroll 2
        for (int m = 0; m < 8; ++m) {
            const int Mt = wave * 8 + m;
            s16x8 afrag[2];
            #pragma unroll
            for (int ks = 0; ks < 2; ++ks)
                afrag[ks] = *(const s16x8*)(ws_whid + (((Mt * 2) + ks) * 64 + lane) * 8);
            f32x4 c = {0.f, 0.f, 0.f, 0.f};
            c = __builtin_amdgcn_mfma_f32_16x16x32_bf16(afrag[0], bfrag[0], c, 0, 0, 0);
            c = __builtin_amdgcn_mfma_f32_16x16x32_bf16(afrag[1], bfrag[1], c, 0, 0, 0);
            // lane holds C[d = Mt*16+lg*4+r][p = lr]
            const int d0 = Mt * 16 + lg * 4;
            const float4 bh = *(const float4*)&b_hid[d0];
            s16x4 pp;
            pp[0] = (short)f2bf(c[0] + bh.x);
            pp[1] = (short)f2bf(c[1] + bh.y);
            pp[2] = (short)f2bf(c[2] + bh.z);
            pp[3] = (short)f2bf(c[3] + bh.w);
            *(s16x4*)(sPb + lr * 1024 + ((d0 * 2) ^ ((lr & 7) << 4))) = pp;
        }
    }
    __syncthreads();

    // ---- P3.5: lane-contiguous hidden pass: g = h + proj -> sGb (bf16).
    {
        f32x4 hreg[8];
        #pragma unroll
        for (int c4 = 0; c4 < 8; ++c4) {
            const int fidx = c4 * 256 + tid;          // float4 index in [0, 2048)
            hreg[c4] = *(const f32x4*)&hidden[(size_t)(pg0 + (fidx >> 7)) * DD + (fidx & 127) * 4];
        }
        #pragma unroll
        for (int c4 = 0; c4 < 8; ++c4) {
            const int fidx = c4 * 256 + tid;
            const int p    = fidx >> 7;
            const int d    = (fidx & 127) * 4;
            const int cb   = (d * 2) ^ ((p & 7) << 4);
            const s16x4 pv = *(const s16x4*)(sPb + p * 1024 + cb);
            s16x4 gp;
            gp[0] = (short)f2bf(hreg[c4][0] + bf2f((unsigned short)pv[0]));
            gp[1] = (short)f2bf(hreg[c4][1] + bf2f((unsigned short)pv[1]));
            gp[2] = (short)f2bf(hreg[c4][2] + bf2f((unsigned short)pv[2]));
            gp[3] = (short)f2bf(hreg[c4][3] + bf2f((unsigned short)pv[3]));
            *(s16x4*)(sGb + p * 1024 + cb) = gp;
        }
    }
    __syncthreads();

    // ---- P4: g1T[h][p] GEMM over K=512; A-fragments coalesced (fragment-major)
    {
        float pgate = 0.f;
        f32x4 c[4];
        #pragma unroll
        for (int m = 0; m < 4; ++m) c[m] = (f32x4){0.f, 0.f, 0.f, 0.f};
        #pragma unroll 4
        for (int ks = 0; ks < 16; ++ks) {
            const int ccol = ks * 64 + lg * 16;
            const s16x8 gb = *(const s16x8*)(sGb + lr * 1024 + (ccol ^ ((lr & 7) << 4)));
            #pragma unroll
            for (int m = 0; m < 4; ++m) {
                const int Mt = wave * 4 + m;
                const s16x8 a = *(const s16x8*)(ws_wg1 + ((Mt * 16 + ks) * 64 + lane) * 8);
                c[m] = __builtin_amdgcn_mfma_f32_16x16x32_bf16(a, gb, c[m], 0, 0, 0);
            }
        }
        #pragma unroll
        for (int m = 0; m < 4; ++m) {
            // lane holds C[h = (wave*4+m)*16+lg*4+r][p = lr]
            const int h0 = (wave * 4 + m) * 16 + lg * 4;
            const float4 bg = *(const float4*)&b_g1[h0];
            const float4 w2 = *(const float4*)&W_g2[h0];
            #pragma unroll
            for (int r = 0; r < 4; ++r) {
                const float x = c[m][r] + ((const float*)&bg)[r];
                const float gl = 0.5f * x * (1.0f + erff(x * 0.70710678118654752f));
                pgate += gl * ((const float*)&w2)[r];
            }
        }
        pgate += __shfl_xor(pgate, 16);
        pgate += __shfl_xor(pgate, 32);
        if (lane < 16) sGpart[wave][lane] = pgate;
    }
    __syncthreads();
    if (tid < TP) {
        const float s = sGpart[0][tid] + sGpart[1][tid] + sGpart[2][tid] + sGpart[3][tid] + b_g2[0];
        sGate[tid] = 1.0f / (1.0f + expf(-s));
    }
    __syncthreads();

    // ---- P6: out = g - (1-gate)*proj, plain cached float4 stores
    {
        #pragma unroll
        for (int c4 = 0; c4 < 8; ++c4) {
            const int fidx = c4 * 256 + tid;          // float4 index in [0, 2048)
            const int p    = fidx >> 7;               // 128 float4 per position
            const int d    = (fidx & 127) * 4;
            const float cg = 1.0f - sGate[p];
            const size_t row = (size_t)(pg0 + p) * DD;
            const int cb = (d * 2) ^ ((p & 7) << 4);
            const s16x4 gv = *(const s16x4*)(sGb + p * 1024 + cb);
            const s16x4 pv = *(const s16x4*)(sPb + p * 1024 + cb);
            f32x4 o;
            o[0] = bf2f((unsigned short)gv[0]) - cg * bf2f((unsigned short)pv[0]);
            o[1] = bf2f((unsigned short)gv[1]) - cg * bf2f((unsigned short)pv[1]);
            o[2] = bf2f((unsigned short)gv[2]) - cg * bf2f((unsigned short)pv[2]);
            o[3] = bf2f((unsigned short)gv[3]) - cg * bf2f((unsigned short)pv[3]);
            *(f32x4*)&out[row + d] = o;
        }
    }
}

extern "C" void kernel_launch(void* const* d_in, const int* in_sizes, int n_in,
                              void* d_out, int out_size, void* d_ws, size_t ws_size,
                              hipStream_t stream) {
    const int*   tok    = (const int*)  d_in[0];
    const float* hidden = (const float*)d_in[1];
    const float* emb    = (const float*)d_in[2];
    const float* W_hid  = (const float*)d_in[3];
    const float* b_hid  = (const float*)d_in[4];
    const float* W_g1   = (const float*)d_in[5];
    const float* b_g1   = (const float*)d_in[6];
    const float* W_g2   = (const float*)d_in[7];
    const float* b_g2   = (const float*)d_in[8];
    const int*   seeds  = (const int*)  d_in[9];
    const int*   p_hr   = (const int*)  d_in[10];
    const int*   p_mn   = (const int*)  d_in[11];
    float* out = (float*)d_out;
    unsigned short* ws_bf = (unsigned short*)d_ws;

    convert_weights<<<dim3((G1 * DD + 255) / 256), dim3(256), 0, stream>>>(W_hid, W_g1, ws_bf);

    const int npos = in_sizes[1] / DD;   // B*T
    engram_mfma<<<dim3(npos / TP), dim3(256), 0, stream>>>(
        tok, hidden, emb, b_hid, b_g1, W_g2, b_g2, seeds, p_hr, p_mn, ws_bf, out);
}